// Round 2
// baseline (479.689 us; speedup 1.0000x reference)
//
#include <hip/hip_runtime.h>

// AssociativeMemoryStep — chunked linear-attention reformulation, fp32 (VALU).
//
//   xb   = x @ basis                       [B*T,128]
//   qkv  = xb @ [q|k|v]_coeffs.T           [B*T,768]
//   L_g  = sum_{s in g} d^{s_loc} k_s v_s^T   (per b, chunk)  [C,C]
//   S_g  = L_{g+1} + d^Tc S_{g+1}          (reverse scan, S_{G-1}=0)
//   retr[t] = sum_{s>t,same chunk} d^{s-t-1}(q_t.k_s) v_s + d^{Tc-1-t_loc} q_t^T S_g
//   out  = (retr @ o_coeffs) @ basis.T * out_scale
//
// B=4 T=4096 V=1024 F=2*NB=128 C=256, chunk Tc=64 (G=64).

#define Bb 4
#define Tt 4096
#define Vv 1024
#define Ff 128
#define Cc 256
#define TC 64
#define Gg (Tt / TC)
#define QLD 768  // q|k|v row stride

__device__ __forceinline__ float dsigmoid(const float* p) {
    return 1.0f / (1.0f + expf(-p[0]));
}

// ---------------------------------------------------------------- setup
__global__ __launch_bounds__(256) void setup_transpose(
    const float* __restrict__ basis, const float* __restrict__ qc,
    const float* __restrict__ kc, const float* __restrict__ vc,
    float* __restrict__ basisT, float* __restrict__ wqkv)
{
    int idx = blockIdx.x * 256 + threadIdx.x;
    if (idx < Ff * Vv) {
        int f = idx / Vv, v = idx % Vv;
        basisT[idx] = basis[v * Ff + f];
    }
    if (idx < Ff * 768) {
        int f = idx / 768, col = idx % 768;
        int sel = col >> 8, c = col & 255;
        const float* src = (sel == 0) ? qc : ((sel == 1) ? kc : vc);
        wqkv[idx] = src[c * Ff + f];
    }
}

// ---------------------------------------------------------------- generic GEMM
// C[M,N] = alpha * A[M,K] @ W[K,N].  BM=64 BN=128 BK=16, 256 thr, 4x8/thread.
// Per-thread cols: {tx*4..+3} and {tx*4+64..+67} (conflict-free b_sm reads).
__global__ __launch_bounds__(256) void gemm64x128(
    const float* __restrict__ A, const float* __restrict__ W,
    float* __restrict__ Co, int K, int ldA, int ldW, int ldC,
    const float* __restrict__ alpha_ptr)
{
    __shared__ float a_sm[16][68];   // [k][m] transposed
    __shared__ float b_sm[16][128];  // [k][n]
    const int tid = threadIdx.x;
    const size_t row0 = (size_t)blockIdx.x * 64;
    const int col0 = blockIdx.y * 128;
    const int ty = tid >> 4, tx = tid & 15;

    float acc[4][8];
#pragma unroll
    for (int i = 0; i < 4; ++i)
#pragma unroll
        for (int j = 0; j < 8; ++j) acc[i][j] = 0.f;

    const int ar = tid >> 2;          // 0..63
    const int ac = (tid & 3) << 2;    // 0,4,8,12
    const int br = tid >> 5;          // 0..7
    const int bc = (tid & 31) << 2;   // 0..124

    const float* Ab = A + (row0 + ar) * (size_t)ldA + ac;
    const float* Wb0 = W + (size_t)br * ldW + col0 + bc;
    const float* Wb1 = W + (size_t)(br + 8) * ldW + col0 + bc;

    for (int k0 = 0; k0 < K; k0 += 16) {
        float4 av = *(const float4*)(Ab + k0);
        float4 bv0 = *(const float4*)(Wb0 + (size_t)k0 * ldW);
        float4 bv1 = *(const float4*)(Wb1 + (size_t)k0 * ldW);
        a_sm[ac + 0][ar] = av.x; a_sm[ac + 1][ar] = av.y;
        a_sm[ac + 2][ar] = av.z; a_sm[ac + 3][ar] = av.w;
        *(float4*)&b_sm[br][bc] = bv0;
        *(float4*)&b_sm[br + 8][bc] = bv1;
        __syncthreads();
#pragma unroll
        for (int kk = 0; kk < 16; ++kk) {
            float4 a = *(const float4*)&a_sm[kk][ty << 2];
            float4 b0 = *(const float4*)&b_sm[kk][tx << 2];
            float4 b1 = *(const float4*)&b_sm[kk][(tx << 2) + 64];
            float as[4] = {a.x, a.y, a.z, a.w};
            float bs[8] = {b0.x, b0.y, b0.z, b0.w, b1.x, b1.y, b1.z, b1.w};
#pragma unroll
            for (int i = 0; i < 4; ++i)
#pragma unroll
                for (int j = 0; j < 8; ++j)
                    acc[i][j] = fmaf(as[i], bs[j], acc[i][j]);
        }
        __syncthreads();
    }
    const float alpha = alpha_ptr ? alpha_ptr[0] : 1.0f;
#pragma unroll
    for (int i = 0; i < 4; ++i) {
        float* crow = Co + (row0 + ty * 4 + i) * (size_t)ldC + col0 + tx * 4;
        float4 o0 = {acc[i][0] * alpha, acc[i][1] * alpha, acc[i][2] * alpha, acc[i][3] * alpha};
        float4 o1 = {acc[i][4] * alpha, acc[i][5] * alpha, acc[i][6] * alpha, acc[i][7] * alpha};
        *(float4*)crow = o0;
        *(float4*)(crow + 64) = o1;
    }
}

// ---------------------------------------------------------------- chunk outer products
// L[b,g][c',c] = sum_s d^{s_loc} k[s][c'] v[s][c].  grid: x=8 tiles, y=G, z=B.
__global__ __launch_bounds__(256) void chunk_l_kernel(
    const float* __restrict__ qkv, float* __restrict__ LS,
    const float* __restrict__ dlogit)
{
    __shared__ float a_sm[16][68];    // [s][c'] (k, pre-scaled)
    __shared__ float b_sm[16][128];   // [s][c]  (v)
    __shared__ float dpow_sm[TC];
    const int tid = threadIdx.x;
    const float d = dsigmoid(dlogit);
    if (tid < TC) dpow_sm[tid] = powf(d, (float)tid);
    __syncthreads();

    const int g = blockIdx.y, b = blockIdx.z;
    const int cp0 = (blockIdx.x >> 1) * 64;
    const int c0 = (blockIdx.x & 1) * 128;
    const int ty = tid >> 4, tx = tid & 15;

    float acc[4][8];
#pragma unroll
    for (int i = 0; i < 4; ++i)
#pragma unroll
        for (int j = 0; j < 8; ++j) acc[i][j] = 0.f;

    const int sa = tid >> 4;          // 0..15
    const int ca = (tid & 15) << 2;   // 0..60
    const int sb = tid >> 5;          // 0..7
    const int cb = (tid & 31) << 2;   // 0..124

    const float* kbase = qkv + ((size_t)(b * Tt + g * TC)) * QLD + Cc;
    const float* vbase = qkv + ((size_t)(b * Tt + g * TC)) * QLD + 2 * Cc;

    for (int k0 = 0; k0 < TC; k0 += 16) {
        float w = dpow_sm[k0 + sa];
        float4 kv = *(const float4*)(kbase + (size_t)(k0 + sa) * QLD + cp0 + ca);
        float4 v0 = *(const float4*)(vbase + (size_t)(k0 + sb) * QLD + c0 + cb);
        float4 v1 = *(const float4*)(vbase + (size_t)(k0 + sb + 8) * QLD + c0 + cb);
        float4 kw = {kv.x * w, kv.y * w, kv.z * w, kv.w * w};
        *(float4*)&a_sm[sa][ca] = kw;
        *(float4*)&b_sm[sb][cb] = v0;
        *(float4*)&b_sm[sb + 8][cb] = v1;
        __syncthreads();
#pragma unroll
        for (int kk = 0; kk < 16; ++kk) {
            float4 a = *(const float4*)&a_sm[kk][ty << 2];
            float4 b0 = *(const float4*)&b_sm[kk][tx << 2];
            float4 b1 = *(const float4*)&b_sm[kk][(tx << 2) + 64];
            float as[4] = {a.x, a.y, a.z, a.w};
            float bs[8] = {b0.x, b0.y, b0.z, b0.w, b1.x, b1.y, b1.z, b1.w};
#pragma unroll
            for (int i = 0; i < 4; ++i)
#pragma unroll
                for (int j = 0; j < 8; ++j)
                    acc[i][j] = fmaf(as[i], bs[j], acc[i][j]);
        }
        __syncthreads();
    }
    const size_t lbase = ((size_t)(b * (Gg + 1) + g)) * Cc * Cc;
#pragma unroll
    for (int i = 0; i < 4; ++i) {
        float* crow = LS + lbase + (size_t)(cp0 + ty * 4 + i) * Cc + c0 + tx * 4;
        float4 o0 = {acc[i][0], acc[i][1], acc[i][2], acc[i][3]};
        float4 o1 = {acc[i][4], acc[i][5], acc[i][6], acc[i][7]};
        *(float4*)crow = o0;
        *(float4*)(crow + 64) = o1;
    }
}

// ---------------------------------------------------------------- reverse scan
// S[g] = L[g+1] + d^Tc S[g+1]; S[G-1]=0.  In-place: S[g] -> slot g+1.
// One-deep load prefetch to overlap the dependent FMA chain with HBM latency.
__global__ __launch_bounds__(256) void scan_kernel(
    float* __restrict__ LS, const float* __restrict__ dlogit)
{
    const int e = blockIdx.x * 256 + threadIdx.x;  // 0..C*C-1
    const int b = blockIdx.y;
    const float d = dsigmoid(dlogit);
    const float dTc = powf(d, (float)TC);
    const size_t CC = (size_t)Cc * Cc;
    const size_t base = ((size_t)b * (Gg + 1)) * CC + e;
    float cur = 0.f;
    LS[base + (size_t)Gg * CC] = 0.f;   // S[G-1] at slot G
    float nxt = LS[base + (size_t)(Gg - 1) * CC];   // L[G-1]
    for (int g = Gg - 2; g >= 0; --g) {
        const size_t off = base + (size_t)(g + 1) * CC;
        float L = nxt;
        if (g > 0) nxt = LS[off - CC];  // prefetch L[g] for next iter
        cur = L + dTc * cur;            // S[g] = L[g+1] + dTc*S[g+1]
        LS[off] = cur;                  // store S[g] at slot g+1
    }
}

// ---------------------------------------------------------------- intra + inter attention
// One block per (g,b): retr[64,256] = masked-decay(Q K^T) V + d^{Tc-1-t} Q S_g
__global__ __launch_bounds__(256) void attn_kernel(
    const float* __restrict__ qkv, const float* __restrict__ LS,
    float* __restrict__ retr, const float* __restrict__ dlogit)
{
    __shared__ float dpow_sm[TC];
    __shared__ float sT[TC][TC + 4];   // scores transposed [s][t]
    __shared__ float a_sm[16][68];     // [k][t]
    __shared__ float b_sm[16][256];    // [k][n]
    const int tid = threadIdx.x;
    const int g = blockIdx.x, b = blockIdx.y;
    const float d = dsigmoid(dlogit);
    if (tid < TC) dpow_sm[tid] = powf(d, (float)tid);

    const float* qbase = qkv + ((size_t)(b * Tt + g * TC)) * QLD;
    const float* kbase = qbase + Cc;
    const float* vbase = qbase + 2 * Cc;

    // ---- phase 1: scores[t,s] = q_t . k_s   (M=64,N=64,K=256)
    const int ty = tid >> 4, tx = tid & 15;
    const int lr = tid >> 2;          // 0..63
    const int lc = (tid & 3) << 2;    // 0,4,8,12
    float acc1[4][4];
#pragma unroll
    for (int i = 0; i < 4; ++i)
#pragma unroll
        for (int j = 0; j < 4; ++j) acc1[i][j] = 0.f;

    for (int k0 = 0; k0 < Cc; k0 += 16) {
        float4 qv = *(const float4*)(qbase + (size_t)lr * QLD + k0 + lc);
        float4 kv = *(const float4*)(kbase + (size_t)lr * QLD + k0 + lc);
        a_sm[lc + 0][lr] = qv.x; a_sm[lc + 1][lr] = qv.y;
        a_sm[lc + 2][lr] = qv.z; a_sm[lc + 3][lr] = qv.w;
        b_sm[lc + 0][lr] = kv.x; b_sm[lc + 1][lr] = kv.y;
        b_sm[lc + 2][lr] = kv.z; b_sm[lc + 3][lr] = kv.w;
        __syncthreads();
#pragma unroll
        for (int kk = 0; kk < 16; ++kk) {
            float4 a = *(const float4*)&a_sm[kk][ty << 2];
            float4 bb = *(const float4*)&b_sm[kk][tx << 2];
            float as[4] = {a.x, a.y, a.z, a.w};
            float bs[4] = {bb.x, bb.y, bb.z, bb.w};
#pragma unroll
            for (int i = 0; i < 4; ++i)
#pragma unroll
                for (int j = 0; j < 4; ++j)
                    acc1[i][j] = fmaf(as[i], bs[j], acc1[i][j]);
        }
        __syncthreads();
    }
    // mask + decay, write transposed scores
#pragma unroll
    for (int i = 0; i < 4; ++i) {
#pragma unroll
        for (int j = 0; j < 4; ++j) {
            int t = ty * 4 + i, s = tx * 4 + j;
            sT[s][t] = (s > t) ? acc1[i][j] * dpow_sm[s - t - 1] : 0.f;
        }
    }
    __syncthreads();

    // ---- phase 2: retr = sT^T @ V + (dW*Q) @ S   (M=64,N=256)
    // Per-thread cols: {tx2*4..+3} and {tx2*4+128..+131} (4-way max on b_sm).
    const int ty2 = tid >> 5;    // 0..7  -> t = ty2*8+i
    const int tx2 = tid & 31;
    float acc2[8][8];
#pragma unroll
    for (int i = 0; i < 8; ++i)
#pragma unroll
        for (int j = 0; j < 8; ++j) acc2[i][j] = 0.f;

    const int vr = tid >> 4;           // 0..15
    const int vc4 = (tid & 15) << 4;   // 0,16,..240

    // part A: scores @ v   (K = 64)
    for (int k0 = 0; k0 < TC; k0 += 16) {
#pragma unroll
        for (int jj = 0; jj < 4; ++jj)
            *(float4*)&b_sm[vr][vc4 + jj * 4] =
                *(const float4*)(vbase + (size_t)(k0 + vr) * QLD + vc4 + jj * 4);
        __syncthreads();
#pragma unroll
        for (int kk = 0; kk < 16; ++kk) {
            int s = k0 + kk;
            float4 a0 = *(const float4*)&sT[s][ty2 * 8];
            float4 a1 = *(const float4*)&sT[s][ty2 * 8 + 4];
            float4 b0 = *(const float4*)&b_sm[kk][tx2 << 2];
            float4 b1 = *(const float4*)&b_sm[kk][(tx2 << 2) + 128];
            float as[8] = {a0.x, a0.y, a0.z, a0.w, a1.x, a1.y, a1.z, a1.w};
            float bs[8] = {b0.x, b0.y, b0.z, b0.w, b1.x, b1.y, b1.z, b1.w};
#pragma unroll
            for (int i = 0; i < 8; ++i)
#pragma unroll
                for (int j = 0; j < 8; ++j)
                    acc2[i][j] = fmaf(as[i], bs[j], acc2[i][j]);
        }
        __syncthreads();
    }

    // part B: (dW * q) @ S   (K = 256), S_g lives at slot g+1
    const float* Sbase = LS + ((size_t)(b * (Gg + 1) + g + 1)) * Cc * Cc;
    for (int k0 = 0; k0 < Cc; k0 += 16) {
        float4 qv = *(const float4*)(qbase + (size_t)lr * QLD + k0 + lc);
        float wq = dpow_sm[TC - 1 - lr];
        __syncthreads();
        a_sm[lc + 0][lr] = qv.x * wq; a_sm[lc + 1][lr] = qv.y * wq;
        a_sm[lc + 2][lr] = qv.z * wq; a_sm[lc + 3][lr] = qv.w * wq;
#pragma unroll
        for (int jj = 0; jj < 4; ++jj)
            *(float4*)&b_sm[vr][vc4 + jj * 4] =
                *(const float4*)(Sbase + (size_t)(k0 + vr) * Cc + vc4 + jj * 4);
        __syncthreads();
#pragma unroll
        for (int kk = 0; kk < 16; ++kk) {
            float4 a0 = *(const float4*)&a_sm[kk][ty2 * 8];
            float4 a1 = *(const float4*)&a_sm[kk][ty2 * 8 + 4];
            float4 b0 = *(const float4*)&b_sm[kk][tx2 << 2];
            float4 b1 = *(const float4*)&b_sm[kk][(tx2 << 2) + 128];
            float as[8] = {a0.x, a0.y, a0.z, a0.w, a1.x, a1.y, a1.z, a1.w};
            float bs[8] = {b0.x, b0.y, b0.z, b0.w, b1.x, b1.y, b1.z, b1.w};
#pragma unroll
            for (int i = 0; i < 8; ++i)
#pragma unroll
                for (int j = 0; j < 8; ++j)
                    acc2[i][j] = fmaf(as[i], bs[j], acc2[i][j]);
        }
    }

    float* rbase = retr + ((size_t)(b * Tt + g * TC)) * Cc;
#pragma unroll
    for (int i = 0; i < 8; ++i) {
        float* crow = rbase + (size_t)(ty2 * 8 + i) * Cc + tx2 * 4;
        float4 o0 = {acc2[i][0], acc2[i][1], acc2[i][2], acc2[i][3]};
        float4 o1 = {acc2[i][4], acc2[i][5], acc2[i][6], acc2[i][7]};
        *(float4*)crow = o0;
        *(float4*)(crow + 128) = o1;
    }
}

// ---------------------------------------------------------------- launch
extern "C" void kernel_launch(void* const* d_in, const int* in_sizes, int n_in,
                              void* d_out, int out_size, void* d_ws, size_t ws_size,
                              hipStream_t stream) {
    const float* x      = (const float*)d_in[0];
    const float* basis  = (const float*)d_in[1];
    const float* qc     = (const float*)d_in[2];
    const float* kc     = (const float*)d_in[3];
    const float* vc     = (const float*)d_in[4];
    const float* oc     = (const float*)d_in[5];
    const float* dlogit = (const float*)d_in[6];
    const float* oscale = (const float*)d_in[7];
    float* out = (float*)d_out;

    float* w = (float*)d_ws;
    float* basisT = w;  w += (size_t)Ff * Vv;
    float* wqkv   = w;  w += (size_t)Ff * 768;
    float* xb     = w;  w += (size_t)Bb * Tt * Ff;
    float* qkv    = w;  w += (size_t)Bb * Tt * QLD;
    float* LS     = w;  w += (size_t)Bb * (Gg + 1) * Cc * Cc;
    float* retr   = w;  w += (size_t)Bb * Tt * Cc;
    float* ro     = w;  w += (size_t)Bb * Tt * Ff;
    // total ~153 MB of d_ws

    setup_transpose<<<512, 256, 0, stream>>>(basis, qc, kc, vc, basisT, wqkv);
    // xb = x @ basis : M=16384 K=1024 N=128
    gemm64x128<<<dim3(Bb * Tt / 64, Ff / 128), 256, 0, stream>>>(
        x, basis, xb, Vv, Vv, Ff, Ff, nullptr);
    // qkv = xb @ wqkv : K=128 N=768
    gemm64x128<<<dim3(Bb * Tt / 64, 768 / 128), 256, 0, stream>>>(
        xb, wqkv, qkv, Ff, Ff, QLD, QLD, nullptr);
    // chunk outer products
    chunk_l_kernel<<<dim3(8, Gg, Bb), 256, 0, stream>>>(qkv, LS, dlogit);
    // reverse scan over chunks
    scan_kernel<<<dim3(Cc * Cc / 256, Bb), 256, 0, stream>>>(LS, dlogit);
    // intra-chunk + state attention
    attn_kernel<<<dim3(Gg, Bb), 256, 0, stream>>>(qkv, LS, retr, dlogit);
    // ro = retr @ o_coeffs : K=256 N=128
    gemm64x128<<<dim3(Bb * Tt / 64, Ff / 128), 256, 0, stream>>>(
        retr, oc, ro, Cc, Cc, Ff, Ff, nullptr);
    // out = ro @ basisT * out_scale : K=128 N=1024
    gemm64x128<<<dim3(Bb * Tt / 64, Vv / 128), 256, 0, stream>>>(
        ro, basisT, out, Ff, Ff, Vv, Vv, oscale);
}

// Round 3
// 304.181 us; speedup vs baseline: 1.5770x; 1.5770x over previous
//
#include <hip/hip_runtime.h>

// AssociativeMemoryStep — chunked linear attention.
// Round 3: big GEMMs on bf16 MFMA (fp32 accum); chunk_l/scan/attn stay fp32 VALU
// (loads converted to bf16). Output projection fused via o_w = basis@oc.T.
//
// B=4 T=4096 V=1024 F=128 C=256, chunk Tc=64 (G=64).

#define Bb 4
#define Tt 4096
#define Vv 1024
#define Ff 128
#define Cc 256
#define TC 64
#define Gg (Tt / TC)
#define QLD 768  // q|k|v row stride (elements)

typedef __attribute__((ext_vector_type(8))) short short8;
typedef __attribute__((ext_vector_type(4))) float f32x4;

__device__ __forceinline__ float dsigmoid(const float* p) {
    return 1.0f / (1.0f + expf(-p[0]));
}
__device__ __forceinline__ ushort f2bf(float f) {
    unsigned u = __float_as_uint(f);
    u = (u + 0x7FFFu + ((u >> 16) & 1u)) >> 16;
    return (ushort)u;
}
__device__ __forceinline__ float bf2f(ushort u) {
    return __uint_as_float(((unsigned)u) << 16);
}

// ---------------------------------------------------------------- weight prep
__global__ __launch_bounds__(256) void prep_weights(
    const float* __restrict__ basis, const float* __restrict__ qc,
    const float* __restrict__ kc, const float* __restrict__ vc,
    const float* __restrict__ oc,
    ushort* __restrict__ basisTb,   // [128][1024] = basis^T bf16
    ushort* __restrict__ qkvc,      // [768][128]  = concat(qc,kc,vc) bf16
    ushort* __restrict__ ocb)       // [256][128]  = oc bf16
{
    int i = blockIdx.x * 256 + threadIdx.x;
    if (i < Ff * Vv) {
        int f = i >> 10, v = i & 1023;
        basisTb[i] = f2bf(basis[v * Ff + f]);
    }
    if (i < 768 * Ff) {
        int ch = i >> 7, f = i & 127;
        const float* src = ch < 256 ? qc : (ch < 512 ? kc : vc);
        qkvc[i] = f2bf(src[(ch & 255) * Ff + f]);
    }
    if (i < Cc * Ff) ocb[i] = f2bf(oc[i]);
}

// ---------------------------------------------------------------- MFMA GEMM
// C[M,N] = A[M,K] @ Bt[N,K]^T.  BM=BN=128, BK=32, 256 thr = 4 waves (2x2),
// each wave 64x64 via 4x4 frags of mfma_f32_16x16x32_bf16.
// AMODE: 0 = A bf16, 1 = A fp32 (convert in stage).
// OMODE: 0 = bf16 out, 1 = fp32 out * alpha, 2 = fp32 raw, per-z split-K slab.
template<int AMODE, int OMODE>
__global__ __launch_bounds__(256) void mgemm(
    const void* __restrict__ Ap, const ushort* __restrict__ Bt,
    void* __restrict__ Cp, int N_total, int K_total, int ldA, int Ksplit,
    const float* __restrict__ alpha_ptr)
{
    __shared__ ushort Asm[128][40];   // rows padded to 40 shorts (80B)
    __shared__ ushort Bsm[128][40];
    const int tid = threadIdx.x;
    const int row0 = blockIdx.x * 128;
    const int col0 = blockIdx.y * 128;
    const int kb = blockIdx.z * Ksplit;

    const int trow = tid >> 1;          // 0..127
    const int thalf = (tid & 1) * 16;   // 0 or 16 (k elems)

    const int l = tid & 63, w = tid >> 6;
    const int wr = (w >> 1) * 64, wc = (w & 1) * 64;
    const int lrow = l & 15, lk = l >> 4;

    f32x4 acc[4][4];
#pragma unroll
    for (int mi = 0; mi < 4; ++mi)
#pragma unroll
        for (int ni = 0; ni < 4; ++ni) {
            f32x4 z = {0.f, 0.f, 0.f, 0.f};
            acc[mi][ni] = z;
        }

    for (int k0 = kb; k0 < kb + Ksplit; k0 += 32) {
        // ---- stage A
        if (AMODE == 1) {
            const float* ap = (const float*)Ap + (size_t)(row0 + trow) * ldA + k0 + thalf;
            float4 f0 = ((const float4*)ap)[0];
            float4 f1 = ((const float4*)ap)[1];
            float4 f2 = ((const float4*)ap)[2];
            float4 f3 = ((const float4*)ap)[3];
            union { ushort us[16]; int4 i4[2]; } t;
            t.us[0] = f2bf(f0.x); t.us[1] = f2bf(f0.y); t.us[2] = f2bf(f0.z); t.us[3] = f2bf(f0.w);
            t.us[4] = f2bf(f1.x); t.us[5] = f2bf(f1.y); t.us[6] = f2bf(f1.z); t.us[7] = f2bf(f1.w);
            t.us[8] = f2bf(f2.x); t.us[9] = f2bf(f2.y); t.us[10] = f2bf(f2.z); t.us[11] = f2bf(f2.w);
            t.us[12] = f2bf(f3.x); t.us[13] = f2bf(f3.y); t.us[14] = f2bf(f3.z); t.us[15] = f2bf(f3.w);
            *(int4*)&Asm[trow][thalf] = t.i4[0];
            *(int4*)&Asm[trow][thalf + 8] = t.i4[1];
        } else {
            const ushort* ap = (const ushort*)Ap + (size_t)(row0 + trow) * ldA + k0 + thalf;
            *(int4*)&Asm[trow][thalf] = ((const int4*)ap)[0];
            *(int4*)&Asm[trow][thalf + 8] = ((const int4*)ap)[1];
        }
        // ---- stage Bt
        {
            const ushort* bp = Bt + (size_t)(col0 + trow) * K_total + k0 + thalf;
            *(int4*)&Bsm[trow][thalf] = ((const int4*)bp)[0];
            *(int4*)&Bsm[trow][thalf + 8] = ((const int4*)bp)[1];
        }
        __syncthreads();
        short8 af[4], bf[4];
#pragma unroll
        for (int mi = 0; mi < 4; ++mi)
            af[mi] = *(const short8*)&Asm[wr + mi * 16 + lrow][lk * 8];
#pragma unroll
        for (int ni = 0; ni < 4; ++ni)
            bf[ni] = *(const short8*)&Bsm[wc + ni * 16 + lrow][lk * 8];
#pragma unroll
        for (int mi = 0; mi < 4; ++mi)
#pragma unroll
            for (int ni = 0; ni < 4; ++ni)
                acc[mi][ni] = __builtin_amdgcn_mfma_f32_16x16x32_bf16(
                    af[mi], bf[ni], acc[mi][ni], 0, 0, 0);
        __syncthreads();
    }

    // ---- epilogue.  C/D: row=(l>>4)*4+r, col=l&15  [m89-verified]
    const float alpha = (OMODE == 1) ? alpha_ptr[0] : 1.0f;
    size_t slab = (OMODE == 2) ? (size_t)blockIdx.z * (size_t)gridDim.x * 128 * N_total : 0;
#pragma unroll
    for (int mi = 0; mi < 4; ++mi) {
#pragma unroll
        for (int ni = 0; ni < 4; ++ni) {
#pragma unroll
            for (int r = 0; r < 4; ++r) {
                int row = row0 + wr + mi * 16 + lk * 4 + r;
                int col = col0 + wc + ni * 16 + lrow;
                size_t idx = slab + (size_t)row * N_total + col;
                if (OMODE == 0) ((ushort*)Cp)[idx] = f2bf(acc[mi][ni][r]);
                else ((float*)Cp)[idx] = acc[mi][ni][r] * alpha;
            }
        }
    }
}

// ---------------------------------------------------------------- split-K reduce
__global__ __launch_bounds__(256) void reduce_xb(
    const float* __restrict__ p, ushort* __restrict__ xb)
{
    int i = blockIdx.x * 256 + threadIdx.x;   // over (16384*128)/4
    float4 a = ((const float4*)p)[i];
    float4 b = ((const float4*)(p + (size_t)Bb * Tt * Ff))[i];
    ushort4 o;
    o.x = f2bf(a.x + b.x); o.y = f2bf(a.y + b.y);
    o.z = f2bf(a.z + b.z); o.w = f2bf(a.w + b.w);
    ((ushort4*)xb)[i] = o;
}

// ---------------------------------------------------------------- chunk outer products (fp32 VALU, bf16 loads)
__global__ __launch_bounds__(256) void chunk_l_kernel(
    const ushort* __restrict__ qkv, float* __restrict__ LS,
    const float* __restrict__ dlogit)
{
    __shared__ float a_sm[16][68];
    __shared__ float b_sm[16][128];
    __shared__ float dpow_sm[TC];
    const int tid = threadIdx.x;
    const float d = dsigmoid(dlogit);
    if (tid < TC) dpow_sm[tid] = powf(d, (float)tid);
    __syncthreads();

    const int g = blockIdx.y, b = blockIdx.z;
    const int cp0 = (blockIdx.x >> 1) * 64;
    const int c0 = (blockIdx.x & 1) * 128;
    const int ty = tid >> 4, tx = tid & 15;

    float acc[4][8];
#pragma unroll
    for (int i = 0; i < 4; ++i)
#pragma unroll
        for (int j = 0; j < 8; ++j) acc[i][j] = 0.f;

    const int sa = tid >> 4;
    const int ca = (tid & 15) << 2;
    const int sb = tid >> 5;
    const int cb = (tid & 31) << 2;

    const ushort* kbase = qkv + ((size_t)(b * Tt + g * TC)) * QLD + Cc;
    const ushort* vbase = qkv + ((size_t)(b * Tt + g * TC)) * QLD + 2 * Cc;

    for (int k0 = 0; k0 < TC; k0 += 16) {
        float w = dpow_sm[k0 + sa];
        ushort4 kq = *(const ushort4*)(kbase + (size_t)(k0 + sa) * QLD + cp0 + ca);
        ushort4 v0q = *(const ushort4*)(vbase + (size_t)(k0 + sb) * QLD + c0 + cb);
        ushort4 v1q = *(const ushort4*)(vbase + (size_t)(k0 + sb + 8) * QLD + c0 + cb);
        a_sm[sa][ca + 0] = bf2f(kq.x) * w; a_sm[sa][ca + 1] = bf2f(kq.y) * w;
        a_sm[sa][ca + 2] = bf2f(kq.z) * w; a_sm[sa][ca + 3] = bf2f(kq.w) * w;
        float4 v0 = {bf2f(v0q.x), bf2f(v0q.y), bf2f(v0q.z), bf2f(v0q.w)};
        float4 v1 = {bf2f(v1q.x), bf2f(v1q.y), bf2f(v1q.z), bf2f(v1q.w)};
        *(float4*)&b_sm[sb][cb] = v0;
        *(float4*)&b_sm[sb + 8][cb] = v1;
        __syncthreads();
#pragma unroll
        for (int kk = 0; kk < 16; ++kk) {
            float4 a = *(const float4*)&a_sm[kk][ty << 2];
            float4 b0 = *(const float4*)&b_sm[kk][tx << 2];
            float4 b1 = *(const float4*)&b_sm[kk][(tx << 2) + 64];
            float as[4] = {a.x, a.y, a.z, a.w};
            float bs[8] = {b0.x, b0.y, b0.z, b0.w, b1.x, b1.y, b1.z, b1.w};
#pragma unroll
            for (int i = 0; i < 4; ++i)
#pragma unroll
                for (int j = 0; j < 8; ++j)
                    acc[i][j] = fmaf(as[i], bs[j], acc[i][j]);
        }
        __syncthreads();
    }
    const size_t lbase = ((size_t)(b * (Gg + 1) + g)) * Cc * Cc;
#pragma unroll
    for (int i = 0; i < 4; ++i) {
        float* crow = LS + lbase + (size_t)(cp0 + ty * 4 + i) * Cc + c0 + tx * 4;
        float4 o0 = {acc[i][0], acc[i][1], acc[i][2], acc[i][3]};
        float4 o1 = {acc[i][4], acc[i][5], acc[i][6], acc[i][7]};
        *(float4*)crow = o0;
        *(float4*)(crow + 64) = o1;
    }
}

// ---------------------------------------------------------------- reverse scan
__global__ __launch_bounds__(256) void scan_kernel(
    float* __restrict__ LS, const float* __restrict__ dlogit)
{
    const int e = blockIdx.x * 256 + threadIdx.x;
    const int b = blockIdx.y;
    const float d = dsigmoid(dlogit);
    const float dTc = powf(d, (float)TC);
    const size_t CC = (size_t)Cc * Cc;
    const size_t base = ((size_t)b * (Gg + 1)) * CC + e;
    float cur = 0.f;
    LS[base + (size_t)Gg * CC] = 0.f;
    float nxt = LS[base + (size_t)(Gg - 1) * CC];
    for (int g = Gg - 2; g >= 0; --g) {
        const size_t off = base + (size_t)(g + 1) * CC;
        float L = nxt;
        if (g > 0) nxt = LS[off - CC];
        cur = L + dTc * cur;
        LS[off] = cur;
    }
}

// ---------------------------------------------------------------- intra + inter attention (fp32 VALU, bf16 q/k/v)
__global__ __launch_bounds__(256) void attn_kernel(
    const ushort* __restrict__ qkv, const float* __restrict__ LS,
    float* __restrict__ retr, const float* __restrict__ dlogit)
{
    __shared__ float dpow_sm[TC];
    __shared__ float sT[TC][TC + 4];
    __shared__ float a_sm[16][68];
    __shared__ float b_sm[16][256];
    const int tid = threadIdx.x;
    const int g = blockIdx.x, b = blockIdx.y;
    const float d = dsigmoid(dlogit);
    if (tid < TC) dpow_sm[tid] = powf(d, (float)tid);

    const ushort* qbase = qkv + ((size_t)(b * Tt + g * TC)) * QLD;
    const ushort* kbase = qbase + Cc;
    const ushort* vbase = qbase + 2 * Cc;

    // ---- phase 1: scores[t,s] = q_t . k_s
    const int ty = tid >> 4, tx = tid & 15;
    const int lr = tid >> 2;
    const int lc = (tid & 3) << 2;
    float acc1[4][4];
#pragma unroll
    for (int i = 0; i < 4; ++i)
#pragma unroll
        for (int j = 0; j < 4; ++j) acc1[i][j] = 0.f;

    for (int k0 = 0; k0 < Cc; k0 += 16) {
        ushort4 qq = *(const ushort4*)(qbase + (size_t)lr * QLD + k0 + lc);
        ushort4 kq = *(const ushort4*)(kbase + (size_t)lr * QLD + k0 + lc);
        a_sm[lc + 0][lr] = bf2f(qq.x); a_sm[lc + 1][lr] = bf2f(qq.y);
        a_sm[lc + 2][lr] = bf2f(qq.z); a_sm[lc + 3][lr] = bf2f(qq.w);
        b_sm[lc + 0][lr] = bf2f(kq.x); b_sm[lc + 1][lr] = bf2f(kq.y);
        b_sm[lc + 2][lr] = bf2f(kq.z); b_sm[lc + 3][lr] = bf2f(kq.w);
        __syncthreads();
#pragma unroll
        for (int kk = 0; kk < 16; ++kk) {
            float4 a = *(const float4*)&a_sm[kk][ty << 2];
            float4 bb = *(const float4*)&b_sm[kk][tx << 2];
            float as[4] = {a.x, a.y, a.z, a.w};
            float bs[4] = {bb.x, bb.y, bb.z, bb.w};
#pragma unroll
            for (int i = 0; i < 4; ++i)
#pragma unroll
                for (int j = 0; j < 4; ++j)
                    acc1[i][j] = fmaf(as[i], bs[j], acc1[i][j]);
        }
        __syncthreads();
    }
#pragma unroll
    for (int i = 0; i < 4; ++i) {
#pragma unroll
        for (int j = 0; j < 4; ++j) {
            int t = ty * 4 + i, s = tx * 4 + j;
            sT[s][t] = (s > t) ? acc1[i][j] * dpow_sm[s - t - 1] : 0.f;
        }
    }
    __syncthreads();

    // ---- phase 2: retr = sT^T @ V + (dW*Q) @ S
    const int ty2 = tid >> 5;
    const int tx2 = tid & 31;
    float acc2[8][8];
#pragma unroll
    for (int i = 0; i < 8; ++i)
#pragma unroll
        for (int j = 0; j < 8; ++j) acc2[i][j] = 0.f;

    const int vr = tid >> 4;
    const int vc4 = (tid & 15) << 4;

    // part A: scores @ v   (K = 64)
    for (int k0 = 0; k0 < TC; k0 += 16) {
#pragma unroll
        for (int jj = 0; jj < 4; ++jj) {
            ushort4 vq = *(const ushort4*)(vbase + (size_t)(k0 + vr) * QLD + vc4 + jj * 4);
            float4 vf = {bf2f(vq.x), bf2f(vq.y), bf2f(vq.z), bf2f(vq.w)};
            *(float4*)&b_sm[vr][vc4 + jj * 4] = vf;
        }
        __syncthreads();
#pragma unroll
        for (int kk = 0; kk < 16; ++kk) {
            int s = k0 + kk;
            float4 a0 = *(const float4*)&sT[s][ty2 * 8];
            float4 a1 = *(const float4*)&sT[s][ty2 * 8 + 4];
            float4 b0 = *(const float4*)&b_sm[kk][tx2 << 2];
            float4 b1 = *(const float4*)&b_sm[kk][(tx2 << 2) + 128];
            float as[8] = {a0.x, a0.y, a0.z, a0.w, a1.x, a1.y, a1.z, a1.w};
            float bs[8] = {b0.x, b0.y, b0.z, b0.w, b1.x, b1.y, b1.z, b1.w};
#pragma unroll
            for (int i = 0; i < 8; ++i)
#pragma unroll
                for (int j = 0; j < 8; ++j)
                    acc2[i][j] = fmaf(as[i], bs[j], acc2[i][j]);
        }
        __syncthreads();
    }

    // part B: (dW * q) @ S   (K = 256)
    const float* Sbase = LS + ((size_t)(b * (Gg + 1) + g + 1)) * Cc * Cc;
    for (int k0 = 0; k0 < Cc; k0 += 16) {
        ushort4 qq = *(const ushort4*)(qbase + (size_t)lr * QLD + k0 + lc);
        float wq = dpow_sm[TC - 1 - lr];
        __syncthreads();
        a_sm[lc + 0][lr] = bf2f(qq.x) * wq; a_sm[lc + 1][lr] = bf2f(qq.y) * wq;
        a_sm[lc + 2][lr] = bf2f(qq.z) * wq; a_sm[lc + 3][lr] = bf2f(qq.w) * wq;
#pragma unroll
        for (int jj = 0; jj < 4; ++jj)
            *(float4*)&b_sm[vr][vc4 + jj * 4] =
                *(const float4*)(Sbase + (size_t)(k0 + vr) * Cc + vc4 + jj * 4);
        __syncthreads();
#pragma unroll
        for (int kk = 0; kk < 16; ++kk) {
            float4 a0 = *(const float4*)&a_sm[kk][ty2 * 8];
            float4 a1 = *(const float4*)&a_sm[kk][ty2 * 8 + 4];
            float4 b0 = *(const float4*)&b_sm[kk][tx2 << 2];
            float4 b1 = *(const float4*)&b_sm[kk][(tx2 << 2) + 128];
            float as[8] = {a0.x, a0.y, a0.z, a0.w, a1.x, a1.y, a1.z, a1.w};
            float bs[8] = {b0.x, b0.y, b0.z, b0.w, b1.x, b1.y, b1.z, b1.w};
#pragma unroll
            for (int i = 0; i < 8; ++i)
#pragma unroll
                for (int j = 0; j < 8; ++j)
                    acc2[i][j] = fmaf(as[i], bs[j], acc2[i][j]);
        }
    }

    float* rbase = retr + ((size_t)(b * Tt + g * TC)) * Cc;
#pragma unroll
    for (int i = 0; i < 8; ++i) {
        float* crow = rbase + (size_t)(ty2 * 8 + i) * Cc + tx2 * 4;
        float4 o0 = {acc2[i][0], acc2[i][1], acc2[i][2], acc2[i][3]};
        float4 o1 = {acc2[i][4], acc2[i][5], acc2[i][6], acc2[i][7]};
        *(float4*)crow = o0;
        *(float4*)(crow + 128) = o1;
    }
}

// ---------------------------------------------------------------- launch
extern "C" void kernel_launch(void* const* d_in, const int* in_sizes, int n_in,
                              void* d_out, int out_size, void* d_ws, size_t ws_size,
                              hipStream_t stream) {
    const float* x      = (const float*)d_in[0];
    const float* basis  = (const float*)d_in[1];
    const float* qc     = (const float*)d_in[2];
    const float* kc     = (const float*)d_in[3];
    const float* vc     = (const float*)d_in[4];
    const float* oc     = (const float*)d_in[5];
    const float* dlogit = (const float*)d_in[6];
    const float* oscale = (const float*)d_in[7];
    float* out = (float*)d_out;

    char* w = (char*)d_ws;
    ushort* basisTb = (ushort*)w;  w += (size_t)Ff * Vv * 2;        // 256KB
    ushort* qkvc    = (ushort*)w;  w += (size_t)768 * Ff * 2;       // 192KB
    ushort* ocb     = (ushort*)w;  w += (size_t)Cc * Ff * 2;        // 64KB
    ushort* ow      = (ushort*)w;  w += (size_t)Vv * Cc * 2;        // 512KB
    float*  xbp     = (float*)w;   w += (size_t)2 * Bb * Tt * Ff * 4; // 16MB
    ushort* xb      = (ushort*)w;  w += (size_t)Bb * Tt * Ff * 2;   // 4MB
    ushort* qkv     = (ushort*)w;  w += (size_t)Bb * Tt * QLD * 2;  // 25MB
    float*  LS      = (float*)w;   w += (size_t)Bb * (Gg + 1) * Cc * Cc * 4; // 68MB
    float*  retr    = (float*)w;   w += (size_t)Bb * Tt * Cc * 4;   // 16MB

    prep_weights<<<512, 256, 0, stream>>>(basis, qc, kc, vc, oc, basisTb, qkvc, ocb);
    // o_w = basis @ oc^T : [1024,256], K=128
    mgemm<1, 0><<<dim3(8, 2), 256, 0, stream>>>(basis, ocb, ow, Cc, Ff, Ff, Ff, nullptr);
    // xb partials = x @ basis^T^T : split-K 2x512
    mgemm<1, 2><<<dim3(128, 1, 2), 256, 0, stream>>>(x, basisTb, xbp, Ff, Vv, Vv, 512, nullptr);
    reduce_xb<<<2048, 256, 0, stream>>>(xbp, xb);
    // qkv = xb @ qkvc^T : [16384,768], K=128
    mgemm<0, 0><<<dim3(128, 6), 256, 0, stream>>>(xb, qkvc, qkv, QLD, Ff, Ff, Ff, nullptr);
    // chunk outer products -> LS
    chunk_l_kernel<<<dim3(8, Gg, Bb), 256, 0, stream>>>(qkv, LS, dlogit);
    // reverse scan
    scan_kernel<<<dim3(Cc * Cc / 256, Bb), 256, 0, stream>>>(LS, dlogit);
    // intra + inter attention -> retr
    attn_kernel<<<dim3(Gg, Bb), 256, 0, stream>>>(qkv, LS, retr, dlogit);
    // out = retr @ o_w^T * out_scale : [16384,1024], K=256
    mgemm<1, 1><<<dim3(128, 8), 256, 0, stream>>>(retr, ow, out, Vv, Cc, Cc, Cc, oscale);
}

// Round 4
// 243.141 us; speedup vs baseline: 1.9729x; 1.2510x over previous
//
#include <hip/hip_runtime.h>

// AssociativeMemoryStep — chunked linear attention, fully MFMA.
// Round 4: attn/chunk_l/scan moved to MFMA(bf16)/bf16 via K,V transpose.
// B=4 T=4096 V=1024 F=128 C=256, chunk Tc=64 (G=64).

#define Bb 4
#define Tt 4096
#define Vv 1024
#define Ff 128
#define Cc 256
#define TC 64
#define Gg (Tt / TC)
#define QLD 768  // q|k|v row stride (elements)

typedef __attribute__((ext_vector_type(8))) short short8;
typedef __attribute__((ext_vector_type(4))) float f32x4;

__device__ __forceinline__ float dsigmoid(const float* p) {
    return 1.0f / (1.0f + expf(-p[0]));
}
__device__ __forceinline__ ushort f2bf(float f) {
    unsigned u = __float_as_uint(f);
    u = (u + 0x7FFFu + ((u >> 16) & 1u)) >> 16;
    return (ushort)u;
}
__device__ __forceinline__ float bf2f(ushort u) {
    return __uint_as_float(((unsigned)u) << 16);
}

// ---------------------------------------------------------------- weight prep
__global__ __launch_bounds__(256) void prep_weights(
    const float* __restrict__ basis, const float* __restrict__ qc,
    const float* __restrict__ kc, const float* __restrict__ vc,
    const float* __restrict__ oc,
    ushort* __restrict__ basisTb,   // [128][1024] = basis^T bf16
    ushort* __restrict__ qkvc,      // [768][128]  = concat(qc,kc,vc) bf16
    ushort* __restrict__ ocb)       // [256][128]  = oc bf16
{
    int i = blockIdx.x * 256 + threadIdx.x;
    if (i < Ff * Vv) {
        int f = i >> 10, v = i & 1023;
        basisTb[i] = f2bf(basis[v * Ff + f]);
    }
    if (i < 768 * Ff) {
        int ch = i >> 7, f = i & 127;
        const float* src = ch < 256 ? qc : (ch < 512 ? kc : vc);
        qkvc[i] = f2bf(src[(ch & 255) * Ff + f]);
    }
    if (i < Cc * Ff) ocb[i] = f2bf(oc[i]);
}

// ---------------------------------------------------------------- MFMA GEMM
// C[M,N] = A[M,K] @ Bt[N,K]^T.  BM=BN=128, BK=32, 4 waves (2x2), 64x64/wave.
// AMODE: 0 = A bf16, 1 = A fp32. OMODE: 0 bf16 out; 1 fp32*alpha; 2 fp32 slab.
template<int AMODE, int OMODE>
__global__ __launch_bounds__(256) void mgemm(
    const void* __restrict__ Ap, const ushort* __restrict__ Bt,
    void* __restrict__ Cp, int N_total, int K_total, int ldA, int Ksplit,
    const float* __restrict__ alpha_ptr)
{
    __shared__ ushort Asm[128][40];
    __shared__ ushort Bsm[128][40];
    const int tid = threadIdx.x;
    const int row0 = blockIdx.x * 128;
    const int col0 = blockIdx.y * 128;
    const int kb = blockIdx.z * Ksplit;

    const int trow = tid >> 1;
    const int thalf = (tid & 1) * 16;

    const int l = tid & 63, w = tid >> 6;
    const int wr = (w >> 1) * 64, wc = (w & 1) * 64;
    const int lrow = l & 15, lk = l >> 4;

    f32x4 acc[4][4];
#pragma unroll
    for (int mi = 0; mi < 4; ++mi)
#pragma unroll
        for (int ni = 0; ni < 4; ++ni) {
            f32x4 z = {0.f, 0.f, 0.f, 0.f};
            acc[mi][ni] = z;
        }

    for (int k0 = kb; k0 < kb + Ksplit; k0 += 32) {
        if (AMODE == 1) {
            const float* ap = (const float*)Ap + (size_t)(row0 + trow) * ldA + k0 + thalf;
            float4 f0 = ((const float4*)ap)[0];
            float4 f1 = ((const float4*)ap)[1];
            float4 f2 = ((const float4*)ap)[2];
            float4 f3 = ((const float4*)ap)[3];
            union { ushort us[16]; int4 i4[2]; } t;
            t.us[0] = f2bf(f0.x); t.us[1] = f2bf(f0.y); t.us[2] = f2bf(f0.z); t.us[3] = f2bf(f0.w);
            t.us[4] = f2bf(f1.x); t.us[5] = f2bf(f1.y); t.us[6] = f2bf(f1.z); t.us[7] = f2bf(f1.w);
            t.us[8] = f2bf(f2.x); t.us[9] = f2bf(f2.y); t.us[10] = f2bf(f2.z); t.us[11] = f2bf(f2.w);
            t.us[12] = f2bf(f3.x); t.us[13] = f2bf(f3.y); t.us[14] = f2bf(f3.z); t.us[15] = f2bf(f3.w);
            *(int4*)&Asm[trow][thalf] = t.i4[0];
            *(int4*)&Asm[trow][thalf + 8] = t.i4[1];
        } else {
            const ushort* ap = (const ushort*)Ap + (size_t)(row0 + trow) * ldA + k0 + thalf;
            *(int4*)&Asm[trow][thalf] = ((const int4*)ap)[0];
            *(int4*)&Asm[trow][thalf + 8] = ((const int4*)ap)[1];
        }
        {
            const ushort* bp = Bt + (size_t)(col0 + trow) * K_total + k0 + thalf;
            *(int4*)&Bsm[trow][thalf] = ((const int4*)bp)[0];
            *(int4*)&Bsm[trow][thalf + 8] = ((const int4*)bp)[1];
        }
        __syncthreads();
        short8 af[4], bf[4];
#pragma unroll
        for (int mi = 0; mi < 4; ++mi)
            af[mi] = *(const short8*)&Asm[wr + mi * 16 + lrow][lk * 8];
#pragma unroll
        for (int ni = 0; ni < 4; ++ni)
            bf[ni] = *(const short8*)&Bsm[wc + ni * 16 + lrow][lk * 8];
#pragma unroll
        for (int mi = 0; mi < 4; ++mi)
#pragma unroll
            for (int ni = 0; ni < 4; ++ni)
                acc[mi][ni] = __builtin_amdgcn_mfma_f32_16x16x32_bf16(
                    af[mi], bf[ni], acc[mi][ni], 0, 0, 0);
        __syncthreads();
    }

    const float alpha = (OMODE == 1) ? alpha_ptr[0] : 1.0f;
    size_t slab = (OMODE == 2) ? (size_t)blockIdx.z * (size_t)gridDim.x * 128 * N_total : 0;
#pragma unroll
    for (int mi = 0; mi < 4; ++mi) {
#pragma unroll
        for (int ni = 0; ni < 4; ++ni) {
#pragma unroll
            for (int r = 0; r < 4; ++r) {
                int row = row0 + wr + mi * 16 + lk * 4 + r;
                int col = col0 + wc + ni * 16 + lrow;
                size_t idx = slab + (size_t)row * N_total + col;
                if (OMODE == 0) ((ushort*)Cp)[idx] = f2bf(acc[mi][ni][r]);
                else ((float*)Cp)[idx] = acc[mi][ni][r] * alpha;
            }
        }
    }
}

// ---------------------------------------------------------------- split-K reduce
__global__ __launch_bounds__(256) void reduce_xb(
    const float* __restrict__ p, ushort* __restrict__ xb)
{
    int i = blockIdx.x * 256 + threadIdx.x;
    float4 a = ((const float4*)p)[i];
    float4 b = ((const float4*)(p + (size_t)Bb * Tt * Ff))[i];
    ushort4 o;
    o.x = f2bf(a.x + b.x); o.y = f2bf(a.y + b.y);
    o.z = f2bf(a.z + b.z); o.w = f2bf(a.w + b.w);
    ((ushort4*)xb)[i] = o;
}

// ---------------------------------------------------------------- K/V transpose
// Kts[b][c][t] = d^{t&63} * K[b][t][c] ; Vt[b][c][t] = V[b][t][c]  (bf16)
__global__ __launch_bounds__(256) void transpose_kv(
    const ushort* __restrict__ qkv, ushort* __restrict__ Kts,
    ushort* __restrict__ Vt, const float* __restrict__ dlogit)
{
    __shared__ ushort tile[64][72];
    __shared__ float dp[64];
    const int tid = threadIdx.x;
    const int t0 = blockIdx.x * 64, c0 = blockIdx.y * 64;
    const int b = blockIdx.z >> 1, mat = blockIdx.z & 1;  // 0=K, 1=V
    const float d = dsigmoid(dlogit);
    if (tid < 64) dp[tid] = powf(d, (float)tid);
    const int coff = 256 + mat * 256 + c0;
#pragma unroll
    for (int j = 0; j < 2; ++j) {
        int row = (tid >> 3) + j * 32;
        int seg = (tid & 7) * 8;
        *(int4*)&tile[row][seg] =
            *(const int4*)(qkv + ((size_t)(b * Tt + t0 + row)) * QLD + coff + seg);
    }
    __syncthreads();
    const int cl = tid & 63, tb = (tid >> 6) * 16;
    ushort* outp = (mat ? Vt : Kts) + ((size_t)(b * Cc + c0 + cl)) * Tt + t0 + tb;
#pragma unroll
    for (int h = 0; h < 2; ++h) {
        union { ushort us[8]; int4 v; } o;
#pragma unroll
        for (int jj = 0; jj < 8; ++jj) {
            int tl = tb + h * 8 + jj;
            ushort val = tile[tl][cl];
            if (mat == 0) val = f2bf(bf2f(val) * dp[tl]);
            o.us[jj] = val;
        }
        *(int4*)(outp + h * 8) = o.v;
    }
}

// ---------------------------------------------------------------- chunk outer products (MFMA)
// LT[b][g][c][c'] = sum_s Vt[c][s] * Kts[c'][s]  (= L[c'][c]), bf16 out.
// grid (4 tiles, G, B); 4 waves 2x2; frags straight from global (L2).
__global__ __launch_bounds__(256) void chunk_lt(
    const ushort* __restrict__ Kts, const ushort* __restrict__ Vt,
    ushort* __restrict__ LT)
{
    const int tid = threadIdx.x;
    const int g = blockIdx.y, b = blockIdx.z;
    const int c0 = (blockIdx.x & 1) * 128, cp0 = (blockIdx.x >> 1) * 128;
    const int w = tid >> 6, l = tid & 63;
    const int wc = (w >> 1) * 64, wcp = (w & 1) * 64;
    const int lrow = l & 15, lk = l >> 4;

    f32x4 acc[4][4];
#pragma unroll
    for (int mi = 0; mi < 4; ++mi)
#pragma unroll
        for (int ni = 0; ni < 4; ++ni) {
            f32x4 z = {0.f, 0.f, 0.f, 0.f};
            acc[mi][ni] = z;
        }
#pragma unroll
    for (int ks = 0; ks < 2; ++ks) {
        short8 af[4], bf[4];
#pragma unroll
        for (int mi = 0; mi < 4; ++mi)
            af[mi] = *(const short8*)(Vt +
                ((size_t)(b * Cc + c0 + wc + mi * 16 + lrow)) * Tt + g * TC + ks * 32 + lk * 8);
#pragma unroll
        for (int ni = 0; ni < 4; ++ni)
            bf[ni] = *(const short8*)(Kts +
                ((size_t)(b * Cc + cp0 + wcp + ni * 16 + lrow)) * Tt + g * TC + ks * 32 + lk * 8);
#pragma unroll
        for (int mi = 0; mi < 4; ++mi)
#pragma unroll
            for (int ni = 0; ni < 4; ++ni)
                acc[mi][ni] = __builtin_amdgcn_mfma_f32_16x16x32_bf16(
                    af[mi], bf[ni], acc[mi][ni], 0, 0, 0);
    }
    ushort* lb = LT + (((size_t)(b * Gg + g)) << 16);
#pragma unroll
    for (int mi = 0; mi < 4; ++mi)
#pragma unroll
        for (int ni = 0; ni < 4; ++ni)
#pragma unroll
            for (int r = 0; r < 4; ++r)
                lb[(size_t)(c0 + wc + mi * 16 + lk * 4 + r) * Cc + cp0 + wcp + ni * 16 + lrow]
                    = f2bf(acc[mi][ni][r]);
}

// ---------------------------------------------------------------- reverse scan
// SbT[b][g] = LT[b][g+1] + d^Tc * SbT-state ; SbT[b][G-1] = 0.  (bf16 in/out)
__global__ __launch_bounds__(64) void scan_kernel(
    const ushort* __restrict__ LT, ushort* __restrict__ SbT,
    const float* __restrict__ dlogit)
{
    const int e = blockIdx.x * 64 + threadIdx.x;
    const int b = blockIdx.y;
    const float d = dsigmoid(dlogit);
    const float dTc = powf(d, (float)TC);
    const size_t CC = (size_t)Cc * Cc;
    const size_t base = (size_t)b * Gg * CC + e;
    SbT[base + (size_t)(Gg - 1) * CC] = 0;
    float cur = 0.f;
    ushort nxt = LT[base + (size_t)(Gg - 1) * CC];  // LT[g+1] for g=G-2
    for (int g = Gg - 2; g >= 0; --g) {
        float L = bf2f(nxt);
        if (g > 0) nxt = LT[base + (size_t)g * CC];  // prefetch
        cur = L + dTc * cur;
        SbT[base + (size_t)g * CC] = f2bf(cur);
    }
}

// ---------------------------------------------------------------- attention (MFMA)
// One block per (g,b), 4 waves. retr[64,256] =
//   P @ V  (P[t][s] = (s>t) d^{s-t-1} q_t.k_s)  +  d^{63-t} * (Q @ SbT^T-rows)
__global__ __launch_bounds__(256) void attn_mfma(
    const ushort* __restrict__ qkv, const ushort* __restrict__ SbT,
    const ushort* __restrict__ Vt, ushort* __restrict__ retrb,
    const float* __restrict__ dlogit)
{
    __shared__ ushort Qsm[64][264];   // row pad 528B -> 2-way banks
    __shared__ ushort Ksm[64][264];
    __shared__ ushort Psm[64][72];    // row pad 144B -> 2-way banks
    __shared__ float dpow[64];
    const int tid = threadIdx.x;
    const int g = blockIdx.x, b = blockIdx.y;
    const float d = dsigmoid(dlogit);
    if (tid < 64) dpow[tid] = powf(d, (float)tid);

    const ushort* qb = qkv + ((size_t)(b * Tt + g * TC)) * QLD;
#pragma unroll
    for (int j = 0; j < 8; ++j) {
        int seg = tid + 256 * j;            // 0..2047
        int row = seg >> 5, sc = (seg & 31) * 8;
        *(int4*)&Qsm[row][sc] = *(const int4*)(qb + (size_t)row * QLD + sc);
        *(int4*)&Ksm[row][sc] = *(const int4*)(qb + (size_t)row * QLD + 256 + sc);
    }
    __syncthreads();

    const int w = tid >> 6, l = tid & 63;
    const int lrow = l & 15, lk = l >> 4;

    // ---- QK^T: wave w computes P cols [w*16, w*16+16)
    f32x4 acc1[4];
#pragma unroll
    for (int mi = 0; mi < 4; ++mi) { f32x4 z = {0.f,0.f,0.f,0.f}; acc1[mi] = z; }
#pragma unroll
    for (int ks = 0; ks < 8; ++ks) {
        short8 bf = *(const short8*)&Ksm[w * 16 + lrow][ks * 32 + lk * 8];
#pragma unroll
        for (int mi = 0; mi < 4; ++mi) {
            short8 af = *(const short8*)&Qsm[mi * 16 + lrow][ks * 32 + lk * 8];
            acc1[mi] = __builtin_amdgcn_mfma_f32_16x16x32_bf16(af, bf, acc1[mi], 0, 0, 0);
        }
    }
#pragma unroll
    for (int mi = 0; mi < 4; ++mi)
#pragma unroll
        for (int r = 0; r < 4; ++r) {
            int t = mi * 16 + lk * 4 + r, s = w * 16 + lrow;
            float p = (s > t) ? acc1[mi][r] * dpow[s - t - 1] : 0.f;
            Psm[t][s] = f2bf(p);
        }
    __syncthreads();

    // ---- retr accumulator: wave w covers cols [w*64, w*64+64)
    f32x4 acc[4][4];
#pragma unroll
    for (int mi = 0; mi < 4; ++mi)
#pragma unroll
        for (int ni = 0; ni < 4; ++ni) {
            f32x4 z = {0.f, 0.f, 0.f, 0.f};
            acc[mi][ni] = z;
        }

    // part B: Q @ S (SbT rows are S columns), K=256
    const ushort* Sg = SbT + (((size_t)(b * Gg + g)) << 16);
#pragma unroll
    for (int ks = 0; ks < 8; ++ks) {
        short8 af[4], bf[4];
#pragma unroll
        for (int mi = 0; mi < 4; ++mi)
            af[mi] = *(const short8*)&Qsm[mi * 16 + lrow][ks * 32 + lk * 8];
#pragma unroll
        for (int ni = 0; ni < 4; ++ni)
            bf[ni] = *(const short8*)(Sg +
                (size_t)(w * 64 + ni * 16 + lrow) * Cc + ks * 32 + lk * 8);
#pragma unroll
        for (int mi = 0; mi < 4; ++mi)
#pragma unroll
            for (int ni = 0; ni < 4; ++ni)
                acc[mi][ni] = __builtin_amdgcn_mfma_f32_16x16x32_bf16(
                    af[mi], bf[ni], acc[mi][ni], 0, 0, 0);
    }
    // scale inter-chunk term by d^{63 - t}
#pragma unroll
    for (int mi = 0; mi < 4; ++mi) {
#pragma unroll
        for (int r = 0; r < 4; ++r) {
            float wq = dpow[63 - (mi * 16 + lk * 4 + r)];
#pragma unroll
            for (int ni = 0; ni < 4; ++ni) acc[mi][ni][r] *= wq;
        }
    }
    // part A: P @ Vt, K=64
#pragma unroll
    for (int ks = 0; ks < 2; ++ks) {
        short8 af[4], bf[4];
#pragma unroll
        for (int mi = 0; mi < 4; ++mi)
            af[mi] = *(const short8*)&Psm[mi * 16 + lrow][ks * 32 + lk * 8];
#pragma unroll
        for (int ni = 0; ni < 4; ++ni)
            bf[ni] = *(const short8*)(Vt +
                ((size_t)(b * Cc + w * 64 + ni * 16 + lrow)) * Tt + g * TC + ks * 32 + lk * 8);
#pragma unroll
        for (int mi = 0; mi < 4; ++mi)
#pragma unroll
            for (int ni = 0; ni < 4; ++ni)
                acc[mi][ni] = __builtin_amdgcn_mfma_f32_16x16x32_bf16(
                    af[mi], bf[ni], acc[mi][ni], 0, 0, 0);
    }

    ushort* rb = retrb + ((size_t)(b * Tt + g * TC)) * Cc;
#pragma unroll
    for (int mi = 0; mi < 4; ++mi)
#pragma unroll
        for (int ni = 0; ni < 4; ++ni)
#pragma unroll
            for (int r = 0; r < 4; ++r)
                rb[(size_t)(mi * 16 + lk * 4 + r) * Cc + w * 64 + ni * 16 + lrow]
                    = f2bf(acc[mi][ni][r]);
}

// ---------------------------------------------------------------- launch
extern "C" void kernel_launch(void* const* d_in, const int* in_sizes, int n_in,
                              void* d_out, int out_size, void* d_ws, size_t ws_size,
                              hipStream_t stream) {
    const float* x      = (const float*)d_in[0];
    const float* basis  = (const float*)d_in[1];
    const float* qc     = (const float*)d_in[2];
    const float* kc     = (const float*)d_in[3];
    const float* vc     = (const float*)d_in[4];
    const float* oc     = (const float*)d_in[5];
    const float* dlogit = (const float*)d_in[6];
    const float* oscale = (const float*)d_in[7];
    float* out = (float*)d_out;

    char* w = (char*)d_ws;
    ushort* basisTb = (ushort*)w;  w += (size_t)Ff * Vv * 2;
    ushort* qkvc    = (ushort*)w;  w += (size_t)768 * Ff * 2;
    ushort* ocb     = (ushort*)w;  w += (size_t)Cc * Ff * 2;
    ushort* ow      = (ushort*)w;  w += (size_t)Vv * Cc * 2;
    float*  xbp     = (float*)w;   w += (size_t)2 * Bb * Tt * Ff * 4;
    ushort* xb      = (ushort*)w;  w += (size_t)Bb * Tt * Ff * 2;
    ushort* qkv     = (ushort*)w;  w += (size_t)Bb * Tt * QLD * 2;
    ushort* Kts     = (ushort*)w;  w += (size_t)Bb * Cc * Tt * 2;
    ushort* Vt      = (ushort*)w;  w += (size_t)Bb * Cc * Tt * 2;
    ushort* LT      = (ushort*)w;  w += (size_t)Bb * Gg * Cc * Cc * 2;
    ushort* SbT     = (ushort*)w;  w += (size_t)Bb * Gg * Cc * Cc * 2;
    ushort* retrb   = (ushort*)w;  w += (size_t)Bb * Tt * Cc * 2;
    // total ~137 MB

    prep_weights<<<512, 256, 0, stream>>>(basis, qc, kc, vc, oc, basisTb, qkvc, ocb);
    // o_w = basis @ oc^T : [1024,256], K=128
    mgemm<1, 0><<<dim3(8, 2), 256, 0, stream>>>(basis, ocb, ow, Cc, Ff, Ff, Ff, nullptr);
    // xb partials = x @ basisT^T : split-K 2x512
    mgemm<1, 2><<<dim3(128, 1, 2), 256, 0, stream>>>(x, basisTb, xbp, Ff, Vv, Vv, 512, nullptr);
    reduce_xb<<<2048, 256, 0, stream>>>(xbp, xb);
    // qkv = xb @ qkvc^T : [16384,768], K=128
    mgemm<0, 0><<<dim3(128, 6), 256, 0, stream>>>(xb, qkvc, qkv, QLD, Ff, Ff, Ff, nullptr);
    // K/V transpose (+decay pre-scale on K)
    transpose_kv<<<dim3(Tt / 64, Cc / 64, Bb * 2), 256, 0, stream>>>(qkv, Kts, Vt, dlogit);
    // per-chunk outer products (MFMA) -> LT bf16
    chunk_lt<<<dim3(4, Gg, Bb), 256, 0, stream>>>(Kts, Vt, LT);
    // reverse scan -> SbT bf16
    scan_kernel<<<dim3(Cc * Cc / 64, Bb), 64, 0, stream>>>(LT, SbT, dlogit);
    // attention core (MFMA) -> retr bf16
    attn_mfma<<<dim3(Gg, Bb), 256, 0, stream>>>(qkv, SbT, Vt, retrb, dlogit);
    // out = retr @ o_w^T * out_scale : [16384,1024], K=256
    mgemm<0, 1><<<dim3(128, 8), 256, 0, stream>>>(retrb, ow, out, Vv, Cc, Cc, Cc, oscale);
}